// Round 8
// baseline (302.943 us; speedup 1.0000x reference)
//
#include <hip/hip_runtime.h>

// LinearConv2D: y[b, o=g*8+n, fi, t] =
//   sum_{d<8, fr<2, w<16} x[b, g*8+d, 2*fi+fr, 4*t+w] * wt[g*8+n, d, 2*fi+fr, w]
// Shapes: x[16,64,128,256] f32, wt[64,8,128,16] f32, out[16,64,64,61] f32.
//
// R15: weights-in-VGPR + sliding window + DPP reduce. R14's asm-prefetch
// pattern aborted twice -> abandoned per pre-registered falsifier. Root
// re-analysis: every prior structure paid a serializing weight-delivery tax
// (LDS broadcast ~12cy x waves x 512 = 20-33us/CU for ANY split; SMEM
// thrashes sK$ - R11). This structure pays none:
//  - lane = (n = lane>>3, dq = lane&7): lane holds wt[g8+n][dq][2fr][16w] =
//    8 quads = 32 VGPR, loaded ONCE, reused 1952 FMAs. No LDS, no SMEM loop.
//  - x sliding window: window for t = quads t..t+3 of the (dq,fr) row; ring
//    of 8 quads/fr, load quad t+6 at t (3-iter lookahead). Each x quad
//    loaded once: the 4x window overlap becomes REGISTER reuse; n-dup across
//    lanes is same-address -> TCP broadcast (free).
//  - d-reduction: 3 DPP ops (quad_perm xor1 0xB1, xor2 0x4E, half-row
//    mirror 0x141) on the VALU pipe - zero LDS traffic, no __shfl.
//  - no lane clamps, no OOB: quads 0..63 consumed exactly; all 64 lanes
//    active every t.
//  - (256,4): demand ~110 VGPR <= cap 128; 2048 blocks x 4 waves = 8192
//    waves = 16 resident/CU (4/SIMD) covering cold-miss latency.
// Per-CU floors: VALU ~15us, HBM ~25us, LDS 0. Predicted: kernel 28-38us,
// dur 185-196, VGPR 110-126, LDS_Block_Size 0, VALUBusy 55-75%, WRITE_SIZE
// ~17MB (spill tripwire). Falsifier: kernel >=45us + low VALUBusy -> ring
// loads sunk -> deepen lookahead next, not structure.

namespace {
constexpr int kF  = 128;
constexpr int kT  = 256;
constexpr int kW  = 16;
constexpr int kNT = 61;   // (256-16)/4 + 1
constexpr int kO  = 64;
constexpr int kFP = 64;   // (128-2)/2 + 1
}

typedef float f32x4 __attribute__((ext_vector_type(4)));

// Sum over the 8-lane dq-group, entirely on the VALU pipe (DPP):
//   xor1: quad_perm [1,0,3,2] = 0xB1
//   xor2: quad_perm [2,3,0,1] = 0x4E
//   quad<->quad: row_half_mirror = 0x141 (valid: after xor1+xor2 every lane
//   of a 4-quad holds that quad's sum, so any bijection between the two
//   quads of the 8-group completes the total).
__device__ __forceinline__ float dpp8_sum(float v) {
  int r;
  r = __builtin_amdgcn_update_dpp(0, __float_as_int(v), 0xB1, 0xF, 0xF, true);
  v += __int_as_float(r);
  r = __builtin_amdgcn_update_dpp(0, __float_as_int(v), 0x4E, 0xF, 0xF, true);
  v += __int_as_float(r);
  r = __builtin_amdgcn_update_dpp(0, __float_as_int(v), 0x141, 0xF, 0xF, true);
  v += __int_as_float(r);
  return v;
}

__global__ __launch_bounds__(256, 4)
void lc2d_kernel(const float* __restrict__ x,
                 const float* __restrict__ wt,
                 float* __restrict__ out) {
  const int lane = threadIdx.x & 63;
  const int wv   = threadIdx.x >> 6;   // wave -> b
  const int n    = lane >> 3;          // output filter within group
  const int dq   = lane & 7;           // depth channel within group
  const int fi   = blockIdx.x;         // 0..63
  const int g    = blockIdx.y;         // 0..7
  const int b    = blockIdx.z * 4 + wv;

  // Per-lane weights: wt[(g*8+n)][dq][2*fi+fr][w], fr=0,1 -> 8 quads (32 f32).
  const float* wb =
      wt + (((size_t)((g * 8 + n) * 8 + dq)) * kF + 2 * fi) * kW;
  f32x4 wq[2][4];
#pragma unroll
  for (int fr = 0; fr < 2; ++fr)
#pragma unroll
    for (int j = 0; j < 4; ++j)
      wq[fr][j] = *(const f32x4*)(wb + fr * kW + 4 * j);

  // Per-lane x rows for (dq, fr): quad index == t (window [4t,4t+16)).
  const float* xr0 =
      x + (((size_t)(b * 64 + g * 8 + dq)) * kF + 2 * fi) * kT;
  const float* xr1 = xr0 + kT;

  // Ring of 8 quads per fr; prologue loads quads 0..5.
  f32x4 q[2][8];
#pragma unroll
  for (int j = 0; j < 6; ++j) {
    q[0][j] = *(const f32x4*)(xr0 + 4 * j);
    q[1][j] = *(const f32x4*)(xr1 + 4 * j);
  }

  float* ob =
      out + (((size_t)b * kO + g * 8 + n) * kFP + fi) * (size_t)kNT;

#pragma unroll
  for (int t = 0; t < kNT; ++t) {
    float p0 = 0.f, p1 = 0.f;
#pragma unroll
    for (int j = 0; j < 4; ++j) {
      const f32x4 a0 = q[0][(t + j) & 7];
      const f32x4 w0 = wq[0][j];
      p0 = fmaf(a0.x, w0.x, p0);
      p0 = fmaf(a0.y, w0.y, p0);
      p0 = fmaf(a0.z, w0.z, p0);
      p0 = fmaf(a0.w, w0.w, p0);
      const f32x4 a1 = q[1][(t + j) & 7];
      const f32x4 w1 = wq[1][j];
      p1 = fmaf(a1.x, w1.x, p1);
      p1 = fmaf(a1.y, w1.y, p1);
      p1 = fmaf(a1.z, w1.z, p1);
      p1 = fmaf(a1.w, w1.w, p1);
    }
    const float p = dpp8_sum(p0 + p1);
    if (dq == 0) ob[t] = p;       // all 8 n-group lanes hold the sum; 1 stores
    if (t <= 57) {                // load quad t+6 (max 63) into freed slot
      q[0][(t + 6) & 7] = *(const f32x4*)(xr0 + 4 * (t + 6));
      q[1][(t + 6) & 7] = *(const f32x4*)(xr1 + 4 * (t + 6));
    }
  }
}

extern "C" void kernel_launch(void* const* d_in, const int* in_sizes, int n_in,
                              void* d_out, int out_size, void* d_ws, size_t ws_size,
                              hipStream_t stream) {
  const float* x  = (const float*)d_in[0];
  const float* wt = (const float*)d_in[1];
  float* out      = (float*)d_out;

  dim3 grid(kFP, 8, 4);   // 64 x 8 x 4 = 2048 blocks x 256 thr = 8192 waves
  lc2d_kernel<<<grid, 256, 0, stream>>>(x, wt, out);
}

// Round 9
// 197.845 us; speedup vs baseline: 1.5312x; 1.5312x over previous
//
#include <hip/hip_runtime.h>
#include <stdint.h>

// LinearConv2D: y[b, o=g*8+n, fi, t] =
//   sum_{d<8, fr<2, w<16} x[b, g*8+d, 2*fi+fr, 4*t+w] * wt[g*8+n, d, 2*fi+fr, w]
// Shapes: x[16,64,128,256] f32, wt[64,8,128,16] f32, out[16,64,64,61] f32.
//
// R16: m97 architecture (guide §5 + Common-mistake #1). Durable lessons from
// R8-R15: (1) hipcc collapses every REGISTER-resident pipeline (R9 VGPR 72,
// R11 VGPR 20, R15 VGPR 44 - all sunk loads to use); (2) volatile-asm
// pipelines abort (R13/R14); (3) segmented per-dq loads are L1-hostile
// (R15, 160us). The one mechanism the compiler cannot collapse: LDS-resident
// double-buffer fed by global_load_lds (async DMA, barrier-gated) - buffers
// aren't registers, loads are contiguous, drain is structural.
//  - block (fi,g) = 512 x 4 waves, all 16 b; wave = b-quad (Sb=4 x Sn=8
//    minimizes LDS reads ~ 1/Sb + 1/Sn under the VGPR budget).
//  - x: per (d,fr)-step stage 16 rows x 1KB into xlds[2][16][64] (32 KB
//    dbuf) via global_load_lds width=16, 4 inst/wave/step; ONE barrier/step.
//  - window reads: add-rotate swizzle p(q)=(q&56)|((q+(q>>3))&7) applied by
//    PRE-SWIZZLING the per-lane GLOBAL source (m173; LDS dest stays linear
//    per m104). Bank histogram == contiguous read (8 lanes/bank b128
//    minimum) vs naive window's 32/bank.
//  - weights: 8KB LDS, broadcast b128 reads (R8-proven).
// Per-CU: FMA 6.5us, HBM ~25us, LDS port ~30us <- binding.
// Predicted: LDS 40960, VGPR 90-130, kernel 33-48us, dur 170-190, VALUBusy
// 30-50%, conflicts ~0, WRITE_SIZE ~17-20MB (spill tripwire).
// Falsifier: kernel >=60us with clean counters -> port model wrong -> SGPR
// weights at 2 blocks/CU (16KB = sK$) next.

namespace {
constexpr int kC  = 64;
constexpr int kF  = 128;
constexpr int kT  = 256;
constexpr int kD  = 8;
constexpr int kN  = 8;
constexpr int kW  = 16;
constexpr int kNT = 61;   // (256-16)/4 + 1
constexpr int kO  = 64;
constexpr int kFP = 64;   // (128-2)/2 + 1
constexpr int kWStride = kD * kF * kW;  // 16384: per-n weight stride (floats)
}

typedef float f32x4 __attribute__((ext_vector_type(4)));

// Async global->LDS, 16B/lane: writes ldsbase + lane*16 from per-lane gsrc.
__device__ __forceinline__ void gload_lds16(const float* gsrc, float* ldsdst) {
  __builtin_amdgcn_global_load_lds(
      (const __attribute__((address_space(1))) uint32_t*)gsrc,
      (__attribute__((address_space(3))) uint32_t*)ldsdst, 16, 0, 0);
}

__global__ __launch_bounds__(256, 2)
void lc2d_kernel(const float* __restrict__ x,
                 const float* __restrict__ wt,
                 float* __restrict__ out) {
  __shared__ f32x4 wlds[512];          // 8 KB: weight slice for (g,fi)
  __shared__ f32x4 xlds[2][16][64];    // 32 KB: x dbuf [buf][b][quad slot]

  const int tid  = threadIdx.x;
  const int lane = tid & 63;
  const int wq   = tid >> 6;     // wave -> b-quad
  const int fi   = blockIdx.x;   // 0..63
  const int g    = blockIdx.y;   // 0..7

  // ---- Stage weights -> LDS (once; coalesced in 128B runs of 8 threads) ---
  // Layout: quad q = n*64 + (d*2+fr)*4 + qq.
  {
    const float* wb = wt + ((size_t)(g * kN) * kD * kF + (size_t)fi * 2) * kW;
#pragma unroll
    for (int r = 0; r < 2; ++r) {
      const int q  = tid + r * 256;
      const int n  = q >> 6;
      const int dd = (q >> 3) & 7;
      const int fr = (q >> 2) & 1;
      const int qq = q & 3;
      wlds[q] = *(const f32x4*)(wb + (size_t)n * kWStride + dd * (kF * kW) +
                                fr * kW + qq * 4);
    }
  }

  // x row bases for this wave's 4 b.
  const float* xrow[4];
#pragma unroll
  for (int bb = 0; bb < 4; ++bb) {
    const int b = wq * 4 + bb;
    xrow[bb] = x + ((size_t)(b * kC + g * kD) * kF + fi * 2) * kT;
  }

  // Staging source pre-swizzle: LDS slot l receives global quad pinv(l), so
  // slot p(q) holds quad q.  p(q)=(q&56)|((q+(q>>3))&7); pinv=(l&56)|((l-(l>>3))&7).
  const int pinv = (lane & 56) | ((lane - (lane >> 3)) & 7);

  // Window read byte-offsets: lane t reads quads t..t+3 at slots p(t+j).
  const int tcl = (lane < kNT) ? lane : (kNT - 1);   // clamp -> q <= 63
  int pj[4];
#pragma unroll
  for (int j = 0; j < 4; ++j) {
    const int q = tcl + j;
    pj[j] = ((q & 56) | ((q + (q >> 3)) & 7)) << 4;   // byte offset in row
  }
  const char* xbase = (const char*)&xlds[0][0][0];

  float acc[4][kN];
#pragma unroll
  for (int bb = 0; bb < 4; ++bb)
#pragma unroll
    for (int n = 0; n < kN; ++n) acc[bb][n] = 0.f;

  // Prologue: stage step 0 (d=0, fr=0) into buf 0.
#pragma unroll
  for (int bb = 0; bb < 4; ++bb)
    gload_lds16(xrow[bb] + 4 * pinv, (float*)&xlds[0][wq * 4 + bb][0]);

  int cur = 0;
  for (int it = 0; it < 16; ++it) {
    __syncthreads();   // staging for `it` landed; buf cur^1 free

    if (it < 15) {     // issue staging for it+1 into the other buffer (async)
      const int nx = it + 1;
      const int roff = (nx >> 1) * (kF * kT) + (nx & 1) * kT;
#pragma unroll
      for (int bb = 0; bb < 4; ++bb)
        gload_lds16(xrow[bb] + roff + 4 * pinv,
                    (float*)&xlds[cur ^ 1][wq * 4 + bb][0]);
    }

    // Compute step `it` from buf cur.
    const int qb = it * 4;   // weight quad base for this (d,fr)
    f32x4 xq[4][4];
#pragma unroll
    for (int bb = 0; bb < 4; ++bb) {
      const char* rb = xbase + cur * 16384 + (wq * 4 + bb) * 1024;
#pragma unroll
      for (int j = 0; j < 4; ++j)
        xq[bb][j] = *(const f32x4*)(rb + pj[j]);
    }
#pragma unroll
    for (int n = 0; n < kN; ++n) {
      const f32x4 w0 = wlds[n * 64 + qb + 0];
      const f32x4 w1 = wlds[n * 64 + qb + 1];
      const f32x4 w2 = wlds[n * 64 + qb + 2];
      const f32x4 w3 = wlds[n * 64 + qb + 3];
#pragma unroll
      for (int bb = 0; bb < 4; ++bb) {
        float a = acc[bb][n];
        a = fmaf(xq[bb][0].x, w0.x, a);
        a = fmaf(xq[bb][0].y, w0.y, a);
        a = fmaf(xq[bb][0].z, w0.z, a);
        a = fmaf(xq[bb][0].w, w0.w, a);
        a = fmaf(xq[bb][1].x, w1.x, a);
        a = fmaf(xq[bb][1].y, w1.y, a);
        a = fmaf(xq[bb][1].z, w1.z, a);
        a = fmaf(xq[bb][1].w, w1.w, a);
        a = fmaf(xq[bb][2].x, w2.x, a);
        a = fmaf(xq[bb][2].y, w2.y, a);
        a = fmaf(xq[bb][2].z, w2.z, a);
        a = fmaf(xq[bb][2].w, w2.w, a);
        a = fmaf(xq[bb][3].x, w3.x, a);
        a = fmaf(xq[bb][3].y, w3.y, a);
        a = fmaf(xq[bb][3].z, w3.z, a);
        a = fmaf(xq[bb][3].w, w3.w, a);
        acc[bb][n] = a;
      }
    }
    cur ^= 1;
  }

  if (lane < kNT) {
    const size_t s = (size_t)kFP * kNT;
#pragma unroll
    for (int bb = 0; bb < 4; ++bb) {
      const int b = wq * 4 + bb;
      float* ob =
          out + (((size_t)b * kO + g * kN) * kFP + fi) * (size_t)kNT + lane;
#pragma unroll
      for (int n = 0; n < kN; ++n) ob[(size_t)n * s] = acc[bb][n];
    }
  }
}

extern "C" void kernel_launch(void* const* d_in, const int* in_sizes, int n_in,
                              void* d_out, int out_size, void* d_ws, size_t ws_size,
                              hipStream_t stream) {
  const float* x  = (const float*)d_in[0];
  const float* wt = (const float*)d_in[1];
  float* out      = (float*)d_out;

  dim3 grid(kFP, 8, 1);   // 64 x 8 = 512 blocks of 256 threads (16 b inside)
  lc2d_kernel<<<grid, 256, 0, stream>>>(x, wt, out);
}